// Round 1
// baseline (4595.659 us; speedup 1.0000x reference)
//
#include <hip/hip_runtime.h>
#include <math.h>

#define N_NODES 100000
#define N_EDGES 1600000
#define D_IN    128
#define D_H     64
#define N_CLS   10
#define BN_EPS  1e-5f

// ---------------- degree / dinv ----------------
__global__ void k_deg(const int* __restrict__ dst, int* __restrict__ cnt, int E) {
    int i = blockIdx.x * blockDim.x + threadIdx.x;
    if (i < E) atomicAdd(&cnt[dst[i]], 1);
}

__global__ void k_dinv(const int* __restrict__ cnt, float* __restrict__ dinv, int n) {
    int i = blockIdx.x * blockDim.x + threadIdx.x;
    if (i < n) dinv[i] = rsqrtf((float)(cnt[i] + 1));  // +1 self loop; always > 0
}

// ---------------- GEMM: hs = dinv[v] * (in[v] @ W^T) ----------------
// W is [64, DIN] row-major (torch Linear layout). 16 nodes / block, 256 threads.
template <int DIN>
__global__ __launch_bounds__(256) void k_gemm(const float* __restrict__ in,
                                              const float* __restrict__ W,
                                              const float* __restrict__ dinv,
                                              float* __restrict__ out) {
    __shared__ float sW[DIN * 65];     // transposed + padded: sW[k*65 + f]
    __shared__ float sx[16][DIN];
    const int t = threadIdx.x;
    const int base = blockIdx.x * 16;  // N_NODES = 16 * 6250 exactly

    for (int i = t; i < DIN * 64; i += 256) {
        int f = i / DIN, k = i % DIN;
        sW[k * 65 + f] = W[i];
    }
    for (int i = t; i < 16 * DIN; i += 256) {
        int n = i / DIN, k = i % DIN;
        sx[n][k] = in[(base + n) * DIN + k];
    }
    __syncthreads();

    const int f = t & 63;
    const int g = t >> 6;  // wave id 0..3, each wave does 4 nodes
    float a0 = 0.f, a1 = 0.f, a2 = 0.f, a3 = 0.f;
#pragma unroll 8
    for (int k = 0; k < DIN; ++k) {
        float wv = sW[k * 65 + f];
        a0 += wv * sx[g * 4 + 0][k];
        a1 += wv * sx[g * 4 + 1][k];
        a2 += wv * sx[g * 4 + 2][k];
        a3 += wv * sx[g * 4 + 3][k];
    }
    int n0 = base + g * 4;
    out[(n0 + 0) * 64 + f] = dinv[n0 + 0] * a0;
    out[(n0 + 1) * 64 + f] = dinv[n0 + 1] * a1;
    out[(n0 + 2) * 64 + f] = dinv[n0 + 2] * a2;
    out[(n0 + 3) * 64 + f] = dinv[n0 + 3] * a3;
}

// ---------------- edge scatter: acc[dst] += hs[src] ----------------
// one thread per (edge, 4 features): float4 gather + 4 scalar atomics
__global__ __launch_bounds__(256) void k_edge(const int* __restrict__ src,
                                              const int* __restrict__ dst,
                                              const float* __restrict__ hs,
                                              float* __restrict__ acc, int E) {
    int gid = blockIdx.x * 256 + threadIdx.x;
    int e = gid >> 4;
    if (e >= E) return;
    int q = (gid & 15) * 4;
    int u = src[e], v = dst[e];
    float4 val = *(const float4*)&hs[u * 64 + q];
    float* p = &acc[v * 64 + q];
    atomicAdd(p + 0, val.x);
    atomicAdd(p + 1, val.y);
    atomicAdd(p + 2, val.z);
    atomicAdd(p + 3, val.w);
}

// ---------------- finalize: y = dinv*(acc + hs) + b, accumulate BN sums ----------------
// 64 nodes / block, 256 threads; wave g handles nodes base+g*16 .. +15
__global__ __launch_bounds__(256) void k_finalize(const float* __restrict__ acc,
                                                  const float* __restrict__ hs,
                                                  const float* __restrict__ dinv,
                                                  const float* __restrict__ bias,
                                                  float* __restrict__ y,
                                                  float* __restrict__ colsum,
                                                  float* __restrict__ colsumsq, int n) {
    const int t = threadIdx.x;
    const int f = t & 63;
    const int g = t >> 6;
    const int base = blockIdx.x * 64;
    const float b = bias[f];
    float s = 0.f, ss = 0.f;
#pragma unroll 4
    for (int i = 0; i < 16; ++i) {
        int v = base + g * 16 + i;
        if (v < n) {
            float yv = dinv[v] * (acc[v * 64 + f] + hs[v * 64 + f]) + b;
            y[v * 64 + f] = yv;
            s += yv;
            ss += yv * yv;
        }
    }
    __shared__ float rs[4][64];
    __shared__ float rss[4][64];
    rs[g][f] = s;
    rss[g][f] = ss;
    __syncthreads();
    if (t < 64) {
        float S = rs[0][t] + rs[1][t] + rs[2][t] + rs[3][t];
        float SS = rss[0][t] + rss[1][t] + rss[2][t] + rss[3][t];
        atomicAdd(&colsum[t], S);
        atomicAdd(&colsumsq[t], SS);
    }
}

// ---------------- BN stats -> scale/shift ----------------
__global__ void k_stats(const float* __restrict__ colsum, const float* __restrict__ colsumsq,
                        const float* __restrict__ gamma, const float* __restrict__ beta,
                        float* __restrict__ scale, float* __restrict__ shift) {
    int f = threadIdx.x;  // 64 threads
    float mean = colsum[f] * (1.0f / N_NODES);
    float var = colsumsq[f] * (1.0f / N_NODES) - mean * mean;  // biased, as torch BN
    float sc = gamma[f] * rsqrtf(var + BN_EPS);
    scale[f] = sc;
    shift[f] = beta[f] - mean * sc;
}

// ---------------- BN apply + exact GELU ----------------
__global__ void k_bngelu(const float* __restrict__ y, const float* __restrict__ scale,
                         const float* __restrict__ shift, float* __restrict__ out, int total) {
    int i = blockIdx.x * blockDim.x + threadIdx.x;
    if (i < total) {
        int f = i & 63;
        float x = y[i] * scale[f] + shift[f];
        out[i] = 0.5f * x * (1.0f + erff(x * 0.70710678118654752f));
    }
}

// ---------------- final linear 64 -> 10 ----------------
__global__ __launch_bounds__(256) void k_out(const float* __restrict__ h,
                                             const float* __restrict__ Wf,
                                             const float* __restrict__ bf,
                                             float* __restrict__ out, int n) {
    __shared__ float sh[64 * 65];      // padded
    __shared__ float sW[N_CLS * 65];
    __shared__ float sb[N_CLS];
    const int t = threadIdx.x;
    const int base = blockIdx.x * 64;
    for (int i = t; i < 64 * 64; i += 256) {
        int v = i >> 6, k = i & 63;
        sh[v * 65 + k] = (base + v < n) ? h[base * 64 + i] : 0.f;
    }
    for (int i = t; i < N_CLS * 64; i += 256) {
        int c = i / 64, k = i % 64;
        sW[c * 65 + k] = Wf[i];
    }
    if (t < N_CLS) sb[t] = bf[t];
    __syncthreads();
    for (int o = t; o < 64 * N_CLS; o += 256) {
        int v = o / N_CLS, c = o % N_CLS;
        if (base + v < n) {
            float a = sb[c];
#pragma unroll
            for (int k = 0; k < 64; ++k) a += sh[v * 65 + k] * sW[c * 65 + k];
            out[(base + v) * N_CLS + c] = a;
        }
    }
}

extern "C" void kernel_launch(void* const* d_in, const int* in_sizes, int n_in,
                              void* d_out, int out_size, void* d_ws, size_t ws_size,
                              hipStream_t stream) {
    const float* x   = (const float*)d_in[0];
    const int*   ei  = (const int*)d_in[1];
    const float* W1  = (const float*)d_in[2];
    const float* b1  = (const float*)d_in[3];
    const float* g1  = (const float*)d_in[4];
    const float* be1 = (const float*)d_in[5];
    const float* W2  = (const float*)d_in[6];
    const float* b2  = (const float*)d_in[7];
    const float* g2  = (const float*)d_in[8];
    const float* be2 = (const float*)d_in[9];
    const float* W3  = (const float*)d_in[10];
    const float* b3  = (const float*)d_in[11];
    const float* g3  = (const float*)d_in[12];
    const float* be3 = (const float*)d_in[13];
    const float* Wf  = (const float*)d_in[14];
    const float* bfc = (const float*)d_in[15];

    const int* src = ei;            // edge_index[0]
    const int* dst = ei + N_EDGES;  // edge_index[1]

    float* A        = (float*)d_ws;             // [N,64] hs / h_next
    float* B        = A + N_NODES * 64;         // [N,64] acc / y
    float* dinv     = B + N_NODES * 64;         // [N]
    int*   cnt      = (int*)(dinv + N_NODES);   // [N]
    float* colsum   = (float*)(cnt + N_NODES);  // [64]
    float* colsumsq = colsum + 64;              // [64]
    float* scale    = colsumsq + 64;            // [64]
    float* shift    = scale + 64;               // [64]

    // degrees (in-degree + self loop)
    hipMemsetAsync(cnt, 0, N_NODES * sizeof(int), stream);
    k_deg<<<(N_EDGES + 255) / 256, 256, 0, stream>>>(dst, cnt, N_EDGES);
    k_dinv<<<(N_NODES + 255) / 256, 256, 0, stream>>>(cnt, dinv, N_NODES);

    const float* Ws[3]  = {W1, W2, W3};
    const float* bs[3]  = {b1, b2, b3};
    const float* gs[3]  = {g1, g2, g3};
    const float* bes[3] = {be1, be2, be3};

    const float* hin = x;
    for (int l = 0; l < 3; ++l) {
        if (l == 0)
            k_gemm<D_IN><<<N_NODES / 16, 256, 0, stream>>>(hin, Ws[l], dinv, A);
        else
            k_gemm<D_H><<<N_NODES / 16, 256, 0, stream>>>(hin, Ws[l], dinv, A);

        hipMemsetAsync(B, 0, (size_t)N_NODES * 64 * sizeof(float), stream);
        k_edge<<<(N_EDGES * 16 + 255) / 256, 256, 0, stream>>>(src, dst, A, B, N_EDGES);

        hipMemsetAsync(colsum, 0, 2 * 64 * sizeof(float), stream);
        k_finalize<<<(N_NODES + 63) / 64, 256, 0, stream>>>(B, A, dinv, bs[l], B,
                                                            colsum, colsumsq, N_NODES);
        k_stats<<<1, 64, 0, stream>>>(colsum, colsumsq, gs[l], bes[l], scale, shift);
        k_bngelu<<<(N_NODES * 64 + 255) / 256, 256, 0, stream>>>(B, scale, shift, A,
                                                                 N_NODES * 64);
        hin = A;
    }

    k_out<<<(N_NODES + 63) / 64, 256, 0, stream>>>(A, Wf, bfc, (float*)d_out, N_NODES);
}

// Round 2
// 945.368 us; speedup vs baseline: 4.8612x; 4.8612x over previous
//
#include <hip/hip_runtime.h>
#include <math.h>

#define N_NODES 100000
#define N_EDGES 1600000
#define D_IN    128
#define D_H     64
#define N_CLS   10
#define BN_EPS  1e-5f

#define SCAN_B  391   // ceil(N_NODES / 256)

__device__ __forceinline__ float gelu_exact(float x) {
    return 0.5f * x * (1.0f + erff(x * 0.70710678118654752f));
}

// ---------------- degree / dinv ----------------
__global__ void k_deg(const int* __restrict__ dst, int* __restrict__ cnt, int E) {
    int i = blockIdx.x * blockDim.x + threadIdx.x;
    if (i < E) atomicAdd(&cnt[dst[i]], 1);
}

__global__ void k_dinv(const int* __restrict__ cnt, float* __restrict__ dinv, int n) {
    int i = blockIdx.x * blockDim.x + threadIdx.x;
    if (i < n) dinv[i] = rsqrtf((float)(cnt[i] + 1));  // +1 self loop
}

// ---------------- CSR build: 2-level exclusive scan ----------------
__global__ __launch_bounds__(256) void k_scan1(const int* __restrict__ cnt,
                                               int* __restrict__ bsum) {
    __shared__ int s[256];
    int t = threadIdx.x;
    int i = blockIdx.x * 256 + t;
    int c = (i < N_NODES) ? cnt[i] : 0;
    s[t] = c;
    __syncthreads();
    for (int off = 128; off > 0; off >>= 1) {
        if (t < off) s[t] += s[t + off];
        __syncthreads();
    }
    if (t == 0) bsum[blockIdx.x] = s[0];
}

__global__ __launch_bounds__(512) void k_scan2(const int* __restrict__ bsum,
                                               int* __restrict__ boff,
                                               int* __restrict__ rowptr) {
    __shared__ int s[512];
    int t = threadIdx.x;
    int c = (t < SCAN_B) ? bsum[t] : 0;
    s[t] = c;
    __syncthreads();
    for (int off = 1; off < 512; off <<= 1) {
        int v = (t >= off) ? s[t - off] : 0;
        __syncthreads();
        s[t] += v;
        __syncthreads();
    }
    if (t < SCAN_B) boff[t] = s[t] - c;  // exclusive
    if (t == 0) rowptr[N_NODES] = N_EDGES;
}

__global__ __launch_bounds__(256) void k_scan3(const int* __restrict__ cnt,
                                               const int* __restrict__ boff,
                                               int* __restrict__ rowptr,
                                               int* __restrict__ cursor) {
    __shared__ int s[256];
    int t = threadIdx.x;
    int i = blockIdx.x * 256 + t;
    int c = (i < N_NODES) ? cnt[i] : 0;
    s[t] = c;
    __syncthreads();
    for (int off = 1; off < 256; off <<= 1) {
        int v = (t >= off) ? s[t - off] : 0;
        __syncthreads();
        s[t] += v;
        __syncthreads();
    }
    if (i < N_NODES) {
        int ex = boff[blockIdx.x] + s[t] - c;  // exclusive global prefix
        rowptr[i] = ex;
        cursor[i] = ex;
    }
}

__global__ void k_fill(const int* __restrict__ src, const int* __restrict__ dst,
                       int* __restrict__ cursor, int* __restrict__ col, int E) {
    int e = blockIdx.x * blockDim.x + threadIdx.x;
    if (e < E) {
        int pos = atomicAdd(&cursor[dst[e]], 1);
        col[pos] = src[e];
    }
}

// ---------------- GEMM: hs = dinv[v] * (act(in[v]) @ W^T) ----------------
// act = identity (layer 0) or BN+GELU using scale/shift of previous layer.
template <int DIN, bool BN>
__global__ __launch_bounds__(256) void k_gemm(const float* __restrict__ in,
                                              const float* __restrict__ W,
                                              const float* __restrict__ dinv,
                                              const float* __restrict__ scale,
                                              const float* __restrict__ shift,
                                              float* __restrict__ out) {
    __shared__ float sW[DIN * 65];     // transposed + padded: sW[k*65 + f]
    __shared__ float sx[16][DIN];
    const int t = threadIdx.x;
    const int base = blockIdx.x * 16;  // N_NODES = 16 * 6250 exactly

    for (int i = t; i < DIN * 64; i += 256) {
        int f = i / DIN, k = i % DIN;
        sW[k * 65 + f] = W[i];
    }
    for (int i = t; i < 16 * DIN; i += 256) {
        int n = i / DIN, k = i % DIN;
        float v = in[(base + n) * DIN + k];
        if (BN) v = gelu_exact(v * scale[k] + shift[k]);
        sx[n][k] = v;
    }
    __syncthreads();

    const int f = t & 63;
    const int g = t >> 6;  // wave id 0..3, each wave does 4 nodes
    float a0 = 0.f, a1 = 0.f, a2 = 0.f, a3 = 0.f;
#pragma unroll 8
    for (int k = 0; k < DIN; ++k) {
        float wv = sW[k * 65 + f];
        a0 += wv * sx[g * 4 + 0][k];
        a1 += wv * sx[g * 4 + 1][k];
        a2 += wv * sx[g * 4 + 2][k];
        a3 += wv * sx[g * 4 + 3][k];
    }
    int n0 = base + g * 4;
    out[(n0 + 0) * 64 + f] = dinv[n0 + 0] * a0;
    out[(n0 + 1) * 64 + f] = dinv[n0 + 1] * a1;
    out[(n0 + 2) * 64 + f] = dinv[n0 + 2] * a2;
    out[(n0 + 3) * 64 + f] = dinv[n0 + 3] * a3;
}

// ---------------- CSR gather + finalize + BN partial sums ----------------
// 1 wave = 64 features of one node; each wave walks 8 nodes.
// y[v] = dinv[v] * (sum_{u->v} hs[u] + hs[v]) + b
__global__ __launch_bounds__(256) void k_gather(const int* __restrict__ rowptr,
                                                const int* __restrict__ col,
                                                const float* __restrict__ hs,
                                                const float* __restrict__ dinv,
                                                const float* __restrict__ bias,
                                                float* __restrict__ y,
                                                float* __restrict__ colsum,
                                                float* __restrict__ colsumsq) {
    const int t = threadIdx.x;
    const int f = t & 63;
    const int w = t >> 6;
    const int base = blockIdx.x * 32 + w * 8;
    const float b = bias[f];
    float s = 0.f, ss = 0.f;
    for (int i = 0; i < 8; ++i) {
        int v = base + i;
        if (v >= N_NODES) break;
        int beg = rowptr[v], end = rowptr[v + 1];
        float acc = hs[v * 64 + f];  // self loop
        int j = beg;
        for (; j + 2 <= end; j += 2) {   // 2-deep pipeline: both loads in flight
            int u0 = col[j], u1 = col[j + 1];
            float x0 = hs[u0 * 64 + f];
            float x1 = hs[u1 * 64 + f];
            acc += x0;
            acc += x1;
        }
        if (j < end) acc += hs[col[j] * 64 + f];
        float yv = dinv[v] * acc + b;
        y[v * 64 + f] = yv;
        s += yv;
        ss += yv * yv;
    }
    __shared__ float rs[4][64];
    __shared__ float rss[4][64];
    rs[w][f] = s;
    rss[w][f] = ss;
    __syncthreads();
    if (t < 64) {
        atomicAdd(&colsum[t], rs[0][t] + rs[1][t] + rs[2][t] + rs[3][t]);
        atomicAdd(&colsumsq[t], rss[0][t] + rss[1][t] + rss[2][t] + rss[3][t]);
    }
}

// ---------------- BN stats -> scale/shift ----------------
__global__ void k_stats(const float* __restrict__ colsum, const float* __restrict__ colsumsq,
                        const float* __restrict__ gamma, const float* __restrict__ beta,
                        float* __restrict__ scale, float* __restrict__ shift) {
    int f = threadIdx.x;  // 64 threads
    float mean = colsum[f] * (1.0f / N_NODES);
    float var = colsumsq[f] * (1.0f / N_NODES) - mean * mean;  // biased, torch BN
    float sc = gamma[f] * rsqrtf(var + BN_EPS);
    scale[f] = sc;
    shift[f] = beta[f] - mean * sc;
}

// ---------------- final linear 64 -> 10 (with BN+GELU of layer 3) ----------------
__global__ __launch_bounds__(256) void k_out(const float* __restrict__ h,
                                             const float* __restrict__ Wf,
                                             const float* __restrict__ bf,
                                             const float* __restrict__ scale,
                                             const float* __restrict__ shift,
                                             float* __restrict__ out, int n) {
    __shared__ float sh[64 * 65];      // padded
    __shared__ float sW[N_CLS * 65];
    __shared__ float sb[N_CLS];
    const int t = threadIdx.x;
    const int base = blockIdx.x * 64;
    for (int i = t; i < 64 * 64; i += 256) {
        int v = i >> 6, k = i & 63;
        float val = 0.f;
        if (base + v < n) {
            float raw = h[base * 64 + i];
            val = gelu_exact(raw * scale[k] + shift[k]);
        }
        sh[v * 65 + k] = val;
    }
    for (int i = t; i < N_CLS * 64; i += 256) {
        int c = i / 64, k = i % 64;
        sW[c * 65 + k] = Wf[i];
    }
    if (t < N_CLS) sb[t] = bf[t];
    __syncthreads();
    for (int o = t; o < 64 * N_CLS; o += 256) {
        int v = o / N_CLS, c = o % N_CLS;
        if (base + v < n) {
            float a = sb[c];
#pragma unroll
            for (int k = 0; k < 64; ++k) a += sh[v * 65 + k] * sW[c * 65 + k];
            out[(base + v) * N_CLS + c] = a;
        }
    }
}

extern "C" void kernel_launch(void* const* d_in, const int* in_sizes, int n_in,
                              void* d_out, int out_size, void* d_ws, size_t ws_size,
                              hipStream_t stream) {
    const float* x   = (const float*)d_in[0];
    const int*   ei  = (const int*)d_in[1];
    const float* W1  = (const float*)d_in[2];
    const float* b1  = (const float*)d_in[3];
    const float* g1  = (const float*)d_in[4];
    const float* be1 = (const float*)d_in[5];
    const float* W2  = (const float*)d_in[6];
    const float* b2  = (const float*)d_in[7];
    const float* g2  = (const float*)d_in[8];
    const float* be2 = (const float*)d_in[9];
    const float* W3  = (const float*)d_in[10];
    const float* b3  = (const float*)d_in[11];
    const float* g3  = (const float*)d_in[12];
    const float* be3 = (const float*)d_in[13];
    const float* Wf  = (const float*)d_in[14];
    const float* bfc = (const float*)d_in[15];

    const int* src = ei;            // edge_index[0]
    const int* dst = ei + N_EDGES;  // edge_index[1]

    float* A        = (float*)d_ws;              // [N,64] hs
    float* B        = A + (size_t)N_NODES * 64;  // [N,64] y
    float* dinv     = B + (size_t)N_NODES * 64;  // [N]
    int*   cnt      = (int*)(dinv + N_NODES);    // [N]
    int*   rowptr   = cnt + N_NODES;             // [N+1]
    int*   cursor   = rowptr + N_NODES + 1;      // [N]
    int*   col      = cursor + N_NODES;          // [E]
    int*   bsum     = col + N_EDGES;             // [512]
    int*   boff     = bsum + 512;                // [512]
    float* colsum   = (float*)(boff + 512);      // [64]
    float* colsumsq = colsum + 64;               // [64]
    float* scale    = colsumsq + 64;             // [64]
    float* shift    = scale + 64;                // [64]

    // ---- CSR build (once per call, reused by all 3 layers) ----
    hipMemsetAsync(cnt, 0, N_NODES * sizeof(int), stream);
    k_deg<<<(N_EDGES + 255) / 256, 256, 0, stream>>>(dst, cnt, N_EDGES);
    k_dinv<<<(N_NODES + 255) / 256, 256, 0, stream>>>(cnt, dinv, N_NODES);
    k_scan1<<<SCAN_B, 256, 0, stream>>>(cnt, bsum);
    k_scan2<<<1, 512, 0, stream>>>(bsum, boff, rowptr);
    k_scan3<<<SCAN_B, 256, 0, stream>>>(cnt, boff, rowptr, cursor);
    k_fill<<<(N_EDGES + 255) / 256, 256, 0, stream>>>(src, dst, cursor, col, N_EDGES);

    const float* Ws[3]  = {W1, W2, W3};
    const float* bs[3]  = {b1, b2, b3};
    const float* gs[3]  = {g1, g2, g3};
    const float* bes[3] = {be1, be2, be3};

    const float* hin = x;
    for (int l = 0; l < 3; ++l) {
        if (l == 0)
            k_gemm<D_IN, false><<<N_NODES / 16, 256, 0, stream>>>(hin, Ws[l], dinv,
                                                                  scale, shift, A);
        else
            k_gemm<D_H, true><<<N_NODES / 16, 256, 0, stream>>>(hin, Ws[l], dinv,
                                                                scale, shift, A);

        hipMemsetAsync(colsum, 0, 2 * 64 * sizeof(float), stream);
        k_gather<<<(N_NODES + 31) / 32, 256, 0, stream>>>(rowptr, col, A, dinv, bs[l],
                                                          B, colsum, colsumsq);
        k_stats<<<1, 64, 0, stream>>>(colsum, colsumsq, gs[l], bes[l], scale, shift);
        hin = B;
    }

    k_out<<<(N_NODES + 63) / 64, 256, 0, stream>>>(B, Wf, bfc, scale, shift,
                                                   (float*)d_out, N_NODES);
}

// Round 3
// 896.445 us; speedup vs baseline: 5.1265x; 1.0546x over previous
//
#include <hip/hip_runtime.h>
#include <math.h>

#define N_NODES 100000
#define N_EDGES 1600000
#define D_IN    128
#define D_H     64
#define N_CLS   10
#define BN_EPS  1e-5f

#define SCAN_B  391   // ceil(N_NODES / 256)

__device__ __forceinline__ float gelu_exact(float x) {
    return 0.5f * x * (1.0f + erff(x * 0.70710678118654752f));
}

// ---------------- degree / dinv ----------------
__global__ void k_deg(const int* __restrict__ dst, int* __restrict__ cnt, int E) {
    int i = blockIdx.x * blockDim.x + threadIdx.x;
    if (i < E) atomicAdd(&cnt[dst[i]], 1);
}

__global__ void k_dinv(const int* __restrict__ cnt, float* __restrict__ dinv, int n) {
    int i = blockIdx.x * blockDim.x + threadIdx.x;
    if (i < n) dinv[i] = rsqrtf((float)(cnt[i] + 1));  // +1 self loop
}

// ---------------- CSR build: 2-level exclusive scan ----------------
__global__ __launch_bounds__(256) void k_scan1(const int* __restrict__ cnt,
                                               int* __restrict__ bsum) {
    __shared__ int s[256];
    int t = threadIdx.x;
    int i = blockIdx.x * 256 + t;
    int c = (i < N_NODES) ? cnt[i] : 0;
    s[t] = c;
    __syncthreads();
    for (int off = 128; off > 0; off >>= 1) {
        if (t < off) s[t] += s[t + off];
        __syncthreads();
    }
    if (t == 0) bsum[blockIdx.x] = s[0];
}

__global__ __launch_bounds__(512) void k_scan2(const int* __restrict__ bsum,
                                               int* __restrict__ boff,
                                               int* __restrict__ rowptr) {
    __shared__ int s[512];
    int t = threadIdx.x;
    int c = (t < SCAN_B) ? bsum[t] : 0;
    s[t] = c;
    __syncthreads();
    for (int off = 1; off < 512; off <<= 1) {
        int v = (t >= off) ? s[t - off] : 0;
        __syncthreads();
        s[t] += v;
        __syncthreads();
    }
    if (t < SCAN_B) boff[t] = s[t] - c;  // exclusive
    if (t == 0) rowptr[N_NODES] = N_EDGES;
}

__global__ __launch_bounds__(256) void k_scan3(const int* __restrict__ cnt,
                                               const int* __restrict__ boff,
                                               int* __restrict__ rowptr,
                                               int* __restrict__ cursor) {
    __shared__ int s[256];
    int t = threadIdx.x;
    int i = blockIdx.x * 256 + t;
    int c = (i < N_NODES) ? cnt[i] : 0;
    s[t] = c;
    __syncthreads();
    for (int off = 1; off < 256; off <<= 1) {
        int v = (t >= off) ? s[t - off] : 0;
        __syncthreads();
        s[t] += v;
        __syncthreads();
    }
    if (i < N_NODES) {
        int ex = boff[blockIdx.x] + s[t] - c;  // exclusive global prefix
        rowptr[i] = ex;
        cursor[i] = ex;
    }
}

__global__ void k_fill(const int* __restrict__ src, const int* __restrict__ dst,
                       int* __restrict__ cursor, int* __restrict__ col, int E) {
    int e = blockIdx.x * blockDim.x + threadIdx.x;
    if (e < E) {
        int pos = atomicAdd(&cursor[dst[e]], 1);
        col[pos] = src[e];
    }
}

// ---------------- GEMM: hs = dinv[v] * (act(in[v]) @ W^T) ----------------
template <int DIN, bool BN>
__global__ __launch_bounds__(256) void k_gemm(const float* __restrict__ in,
                                              const float* __restrict__ W,
                                              const float* __restrict__ dinv,
                                              const float* __restrict__ scale,
                                              const float* __restrict__ shift,
                                              float* __restrict__ out) {
    __shared__ float sW[DIN * 65];     // transposed + padded: sW[k*65 + f]
    __shared__ float sx[16][DIN];
    const int t = threadIdx.x;
    const int base = blockIdx.x * 16;  // N_NODES = 16 * 6250 exactly

    for (int i = t; i < DIN * 64; i += 256) {
        int f = i / DIN, k = i % DIN;
        sW[k * 65 + f] = W[i];
    }
    for (int i = t; i < 16 * DIN; i += 256) {
        int n = i / DIN, k = i % DIN;
        float v = in[(base + n) * DIN + k];
        if (BN) v = gelu_exact(v * scale[k] + shift[k]);
        sx[n][k] = v;
    }
    __syncthreads();

    const int f = t & 63;
    const int g = t >> 6;  // wave id 0..3, each wave does 4 nodes
    float a0 = 0.f, a1 = 0.f, a2 = 0.f, a3 = 0.f;
#pragma unroll 8
    for (int k = 0; k < DIN; ++k) {
        float wv = sW[k * 65 + f];
        a0 += wv * sx[g * 4 + 0][k];
        a1 += wv * sx[g * 4 + 1][k];
        a2 += wv * sx[g * 4 + 2][k];
        a3 += wv * sx[g * 4 + 3][k];
    }
    int n0 = base + g * 4;
    out[(n0 + 0) * 64 + f] = dinv[n0 + 0] * a0;
    out[(n0 + 1) * 64 + f] = dinv[n0 + 1] * a1;
    out[(n0 + 2) * 64 + f] = dinv[n0 + 2] * a2;
    out[(n0 + 3) * 64 + f] = dinv[n0 + 3] * a3;
}

// ---------------- CSR gather + finalize + BN partial sums ----------------
// Wave layout: lane = e*16 + q. Edge slot e (0..3) handles every 4th edge;
// feature quad q (0..15) covers feats [4q, 4q+4) via float4.
// One float4 load instruction per wave fetches 4 FULL rows (1 KB).
// Unroll 2 -> 8 rows + 8 col idx in flight. Slot partials combined via
// __shfl_xor(16/32) per node.
__global__ __launch_bounds__(256) void k_gather(const int* __restrict__ rowptr,
                                                const int* __restrict__ col,
                                                const float* __restrict__ hs,
                                                const float* __restrict__ dinv,
                                                const float* __restrict__ bias,
                                                float* __restrict__ y,
                                                float* __restrict__ colsum,
                                                float* __restrict__ colsumsq) {
    const int t = threadIdx.x;
    const int lane = t & 63;
    const int w = t >> 6;
    const int q = lane & 15;   // feature quad
    const int e = lane >> 4;   // edge slot
    const int base = blockIdx.x * 32 + w * 8;

    const float4 bv = *(const float4*)&bias[q * 4];
    float4 s  = {0.f, 0.f, 0.f, 0.f};
    float4 ss = {0.f, 0.f, 0.f, 0.f};

    for (int i = 0; i < 8; ++i) {
        int v = base + i;
        if (v >= N_NODES) break;
        int beg = rowptr[v], end = rowptr[v + 1];

        float4 acc;
        if (e == 0) {  // self loop on slot 0
            acc = *(const float4*)&hs[(size_t)v * 64 + q * 4];
        } else {
            acc.x = acc.y = acc.z = acc.w = 0.f;
        }

        int j = beg;
        for (; j + 8 <= end; j += 8) {      // 8 rows in flight
            int u0 = col[j + e];
            int u1 = col[j + 4 + e];
            float4 x0 = *(const float4*)&hs[(size_t)u0 * 64 + q * 4];
            float4 x1 = *(const float4*)&hs[(size_t)u1 * 64 + q * 4];
            acc.x += x0.x; acc.y += x0.y; acc.z += x0.z; acc.w += x0.w;
            acc.x += x1.x; acc.y += x1.y; acc.z += x1.z; acc.w += x1.w;
        }
        for (; j < end; j += 4) {           // tail, 4 at a time, predicated
            int idx = j + e;
            int ic = (idx < end) ? idx : (end - 1);   // clamped: no OOB
            int u = col[ic];
            float4 x = *(const float4*)&hs[(size_t)u * 64 + q * 4];
            if (idx < end) {
                acc.x += x.x; acc.y += x.y; acc.z += x.z; acc.w += x.w;
            }
        }

        // combine the 4 edge slots (xor across lanes 16 and 32 apart)
        acc.x += __shfl_xor(acc.x, 16); acc.y += __shfl_xor(acc.y, 16);
        acc.z += __shfl_xor(acc.z, 16); acc.w += __shfl_xor(acc.w, 16);
        acc.x += __shfl_xor(acc.x, 32); acc.y += __shfl_xor(acc.y, 32);
        acc.z += __shfl_xor(acc.z, 32); acc.w += __shfl_xor(acc.w, 32);

        if (e == 0) {
            float d = dinv[v];
            float4 yv;
            yv.x = d * acc.x + bv.x;
            yv.y = d * acc.y + bv.y;
            yv.z = d * acc.z + bv.z;
            yv.w = d * acc.w + bv.w;
            *(float4*)&y[(size_t)v * 64 + q * 4] = yv;
            s.x += yv.x; s.y += yv.y; s.z += yv.z; s.w += yv.w;
            ss.x += yv.x * yv.x; ss.y += yv.y * yv.y;
            ss.z += yv.z * yv.z; ss.w += yv.w * yv.w;
        }
    }

    __shared__ float rs[4][64];
    __shared__ float rss[4][64];
    if (e == 0) {
        rs[w][q * 4 + 0] = s.x;  rs[w][q * 4 + 1] = s.y;
        rs[w][q * 4 + 2] = s.z;  rs[w][q * 4 + 3] = s.w;
        rss[w][q * 4 + 0] = ss.x; rss[w][q * 4 + 1] = ss.y;
        rss[w][q * 4 + 2] = ss.z; rss[w][q * 4 + 3] = ss.w;
    }
    __syncthreads();
    if (t < 64) {
        atomicAdd(&colsum[t], rs[0][t] + rs[1][t] + rs[2][t] + rs[3][t]);
        atomicAdd(&colsumsq[t], rss[0][t] + rss[1][t] + rss[2][t] + rss[3][t]);
    }
}

// ---------------- BN stats -> scale/shift ----------------
__global__ void k_stats(const float* __restrict__ colsum, const float* __restrict__ colsumsq,
                        const float* __restrict__ gamma, const float* __restrict__ beta,
                        float* __restrict__ scale, float* __restrict__ shift) {
    int f = threadIdx.x;  // 64 threads
    float mean = colsum[f] * (1.0f / N_NODES);
    float var = colsumsq[f] * (1.0f / N_NODES) - mean * mean;  // biased, torch BN
    float sc = gamma[f] * rsqrtf(var + BN_EPS);
    scale[f] = sc;
    shift[f] = beta[f] - mean * sc;
}

// ---------------- final linear 64 -> 10 (with BN+GELU of layer 3) ----------------
__global__ __launch_bounds__(256) void k_out(const float* __restrict__ h,
                                             const float* __restrict__ Wf,
                                             const float* __restrict__ bf,
                                             const float* __restrict__ scale,
                                             const float* __restrict__ shift,
                                             float* __restrict__ out, int n) {
    __shared__ float sh[64 * 65];      // padded
    __shared__ float sW[N_CLS * 65];
    __shared__ float sb[N_CLS];
    const int t = threadIdx.x;
    const int base = blockIdx.x * 64;
    for (int i = t; i < 64 * 64; i += 256) {
        int v = i >> 6, k = i & 63;
        float val = 0.f;
        if (base + v < n) {
            float raw = h[base * 64 + i];
            val = gelu_exact(raw * scale[k] + shift[k]);
        }
        sh[v * 65 + k] = val;
    }
    for (int i = t; i < N_CLS * 64; i += 256) {
        int c = i / 64, k = i % 64;
        sW[c * 65 + k] = Wf[i];
    }
    if (t < N_CLS) sb[t] = bf[t];
    __syncthreads();
    for (int o = t; o < 64 * N_CLS; o += 256) {
        int v = o / N_CLS, c = o % N_CLS;
        if (base + v < n) {
            float a = sb[c];
#pragma unroll
            for (int k = 0; k < 64; ++k) a += sh[v * 65 + k] * sW[c * 65 + k];
            out[(base + v) * N_CLS + c] = a;
        }
    }
}

extern "C" void kernel_launch(void* const* d_in, const int* in_sizes, int n_in,
                              void* d_out, int out_size, void* d_ws, size_t ws_size,
                              hipStream_t stream) {
    const float* x   = (const float*)d_in[0];
    const int*   ei  = (const int*)d_in[1];
    const float* W1  = (const float*)d_in[2];
    const float* b1  = (const float*)d_in[3];
    const float* g1  = (const float*)d_in[4];
    const float* be1 = (const float*)d_in[5];
    const float* W2  = (const float*)d_in[6];
    const float* b2  = (const float*)d_in[7];
    const float* g2  = (const float*)d_in[8];
    const float* be2 = (const float*)d_in[9];
    const float* W3  = (const float*)d_in[10];
    const float* b3  = (const float*)d_in[11];
    const float* g3  = (const float*)d_in[12];
    const float* be3 = (const float*)d_in[13];
    const float* Wf  = (const float*)d_in[14];
    const float* bfc = (const float*)d_in[15];

    const int* src = ei;            // edge_index[0]
    const int* dst = ei + N_EDGES;  // edge_index[1]

    float* A        = (float*)d_ws;              // [N,64] hs
    float* B        = A + (size_t)N_NODES * 64;  // [N,64] y
    float* dinv     = B + (size_t)N_NODES * 64;  // [N]
    int*   cnt      = (int*)(dinv + N_NODES);    // [N]
    int*   rowptr   = cnt + N_NODES;             // [N+1]
    int*   cursor   = rowptr + N_NODES + 1;      // [N]
    int*   col      = cursor + N_NODES;          // [E]
    int*   bsum     = col + N_EDGES;             // [512]
    int*   boff     = bsum + 512;                // [512]
    float* colsum   = (float*)(boff + 512);      // [64]
    float* colsumsq = colsum + 64;               // [64]
    float* scale    = colsumsq + 64;             // [64]
    float* shift    = scale + 64;                // [64]

    // ---- CSR build (once per call, reused by all 3 layers) ----
    hipMemsetAsync(cnt, 0, N_NODES * sizeof(int), stream);
    k_deg<<<(N_EDGES + 255) / 256, 256, 0, stream>>>(dst, cnt, N_EDGES);
    k_dinv<<<(N_NODES + 255) / 256, 256, 0, stream>>>(cnt, dinv, N_NODES);
    k_scan1<<<SCAN_B, 256, 0, stream>>>(cnt, bsum);
    k_scan2<<<1, 512, 0, stream>>>(bsum, boff, rowptr);
    k_scan3<<<SCAN_B, 256, 0, stream>>>(cnt, boff, rowptr, cursor);
    k_fill<<<(N_EDGES + 255) / 256, 256, 0, stream>>>(src, dst, cursor, col, N_EDGES);

    const float* Ws[3]  = {W1, W2, W3};
    const float* bs[3]  = {b1, b2, b3};
    const float* gs[3]  = {g1, g2, g3};
    const float* bes[3] = {be1, be2, be3};

    const float* hin = x;
    for (int l = 0; l < 3; ++l) {
        if (l == 0)
            k_gemm<D_IN, false><<<N_NODES / 16, 256, 0, stream>>>(hin, Ws[l], dinv,
                                                                  scale, shift, A);
        else
            k_gemm<D_H, true><<<N_NODES / 16, 256, 0, stream>>>(hin, Ws[l], dinv,
                                                                scale, shift, A);

        hipMemsetAsync(colsum, 0, 2 * 64 * sizeof(float), stream);
        k_gather<<<(N_NODES + 31) / 32, 256, 0, stream>>>(rowptr, col, A, dinv, bs[l],
                                                          B, colsum, colsumsq);
        k_stats<<<1, 64, 0, stream>>>(colsum, colsumsq, gs[l], bes[l], scale, shift);
        hin = B;
    }

    k_out<<<(N_NODES + 63) / 64, 256, 0, stream>>>(B, Wf, bfc, scale, shift,
                                                   (float*)d_out, N_NODES);
}

// Round 4
// 890.922 us; speedup vs baseline: 5.1583x; 1.0062x over previous
//
#include <hip/hip_runtime.h>
#include <math.h>

#define N_NODES 100000
#define N_EDGES 1600000
#define D_IN    128
#define D_H     64
#define N_CLS   10
#define BN_EPS  1e-5f

#define SCAN_B  391   // ceil(N_NODES / 256)
#define STAGE   512   // LDS-staged col entries per wave (8 nodes, avg 128, 34 sigma margin)

__device__ __forceinline__ float gelu_exact(float x) {
    return 0.5f * x * (1.0f + erff(x * 0.70710678118654752f));
}

// ---------------- degree / dinv ----------------
__global__ void k_deg(const int* __restrict__ dst, int* __restrict__ cnt, int E) {
    int i = blockIdx.x * blockDim.x + threadIdx.x;
    if (i < E) atomicAdd(&cnt[dst[i]], 1);
}

__global__ void k_dinv(const int* __restrict__ cnt, float* __restrict__ dinv, int n) {
    int i = blockIdx.x * blockDim.x + threadIdx.x;
    if (i < n) dinv[i] = rsqrtf((float)(cnt[i] + 1));  // +1 self loop
}

// ---------------- CSR build: 2-level exclusive scan ----------------
__global__ __launch_bounds__(256) void k_scan1(const int* __restrict__ cnt,
                                               int* __restrict__ bsum) {
    __shared__ int s[256];
    int t = threadIdx.x;
    int i = blockIdx.x * 256 + t;
    int c = (i < N_NODES) ? cnt[i] : 0;
    s[t] = c;
    __syncthreads();
    for (int off = 128; off > 0; off >>= 1) {
        if (t < off) s[t] += s[t + off];
        __syncthreads();
    }
    if (t == 0) bsum[blockIdx.x] = s[0];
}

__global__ __launch_bounds__(512) void k_scan2(const int* __restrict__ bsum,
                                               int* __restrict__ boff,
                                               int* __restrict__ rowptr) {
    __shared__ int s[512];
    int t = threadIdx.x;
    int c = (t < SCAN_B) ? bsum[t] : 0;
    s[t] = c;
    __syncthreads();
    for (int off = 1; off < 512; off <<= 1) {
        int v = (t >= off) ? s[t - off] : 0;
        __syncthreads();
        s[t] += v;
        __syncthreads();
    }
    if (t < SCAN_B) boff[t] = s[t] - c;  // exclusive
    if (t == 0) rowptr[N_NODES] = N_EDGES;
}

__global__ __launch_bounds__(256) void k_scan3(const int* __restrict__ cnt,
                                               const int* __restrict__ boff,
                                               int* __restrict__ rowptr,
                                               int* __restrict__ cursor) {
    __shared__ int s[256];
    int t = threadIdx.x;
    int i = blockIdx.x * 256 + t;
    int c = (i < N_NODES) ? cnt[i] : 0;
    s[t] = c;
    __syncthreads();
    for (int off = 1; off < 256; off <<= 1) {
        int v = (t >= off) ? s[t - off] : 0;
        __syncthreads();
        s[t] += v;
        __syncthreads();
    }
    if (i < N_NODES) {
        int ex = boff[blockIdx.x] + s[t] - c;  // exclusive global prefix
        rowptr[i] = ex;
        cursor[i] = ex;
    }
}

__global__ void k_fill(const int* __restrict__ src, const int* __restrict__ dst,
                       int* __restrict__ cursor, int* __restrict__ col, int E) {
    int e = blockIdx.x * blockDim.x + threadIdx.x;
    if (e < E) {
        int pos = atomicAdd(&cursor[dst[e]], 1);
        col[pos] = src[e];
    }
}

// ---------------- GEMM: hs = dinv[v] * (act(in[v]) @ W^T) ----------------
template <int DIN, bool BN>
__global__ __launch_bounds__(256) void k_gemm(const float* __restrict__ in,
                                              const float* __restrict__ W,
                                              const float* __restrict__ dinv,
                                              const float* __restrict__ scale,
                                              const float* __restrict__ shift,
                                              float* __restrict__ out) {
    __shared__ float sW[DIN * 65];     // transposed + padded: sW[k*65 + f]
    __shared__ float sx[16][DIN];
    const int t = threadIdx.x;
    const int base = blockIdx.x * 16;  // N_NODES = 16 * 6250 exactly

    for (int i = t; i < DIN * 64; i += 256) {
        int f = i / DIN, k = i % DIN;
        sW[k * 65 + f] = W[i];
    }
    for (int i = t; i < 16 * DIN; i += 256) {
        int n = i / DIN, k = i % DIN;
        float v = in[(base + n) * DIN + k];
        if (BN) v = gelu_exact(v * scale[k] + shift[k]);
        sx[n][k] = v;
    }
    __syncthreads();

    const int f = t & 63;
    const int g = t >> 6;  // wave id 0..3, each wave does 4 nodes
    float a0 = 0.f, a1 = 0.f, a2 = 0.f, a3 = 0.f;
#pragma unroll 8
    for (int k = 0; k < DIN; ++k) {
        float wv = sW[k * 65 + f];
        a0 += wv * sx[g * 4 + 0][k];
        a1 += wv * sx[g * 4 + 1][k];
        a2 += wv * sx[g * 4 + 2][k];
        a3 += wv * sx[g * 4 + 3][k];
    }
    int n0 = base + g * 4;
    out[(n0 + 0) * 64 + f] = dinv[n0 + 0] * a0;
    out[(n0 + 1) * 64 + f] = dinv[n0 + 1] * a1;
    out[(n0 + 2) * 64 + f] = dinv[n0 + 2] * a2;
    out[(n0 + 3) * 64 + f] = dinv[n0 + 3] * a3;
}

// ---------------- CSR gather + finalize + BN partial sums ----------------
// Wave layout: lane = e*16 + q; e = edge slot (0..3), q = feature quad (0..15).
// Each wave owns 8 consecutive nodes -> their CSR col range is CONTIGUOUS.
// Phase A: stage that range into LDS (coalesced). Phase B: row gather with
// addresses from LDS (~30cyc) instead of global (~400cyc) -> no dependent
// global chain; unroll 16 edges/iter -> 4 independent float4 loads in flight.
__global__ __launch_bounds__(256) void k_gather(const int* __restrict__ rowptr,
                                                const int* __restrict__ col,
                                                const float* __restrict__ hs,
                                                const float* __restrict__ dinv,
                                                const float* __restrict__ bias,
                                                float* __restrict__ y,
                                                float* __restrict__ colsum,
                                                float* __restrict__ colsumsq) {
    __shared__ int scol[4][STAGE];
    __shared__ float rs[4][64];
    __shared__ float rss[4][64];

    const int t = threadIdx.x;
    const int lane = t & 63;
    const int w = t >> 6;
    const int q = lane & 15;   // feature quad
    const int e = lane >> 4;   // edge slot
    const int base = blockIdx.x * 32 + w * 8;   // grid covers exactly N_NODES

    const int beg8 = rowptr[base];
    const int end8 = rowptr[base + 8 <= N_NODES ? base + 8 : N_NODES];
    const int cnt8 = end8 - beg8;
    const bool lds_ok = (cnt8 <= STAGE);
    if (lds_ok) {
        for (int k = lane; k < cnt8; k += 64) scol[w][k] = col[beg8 + k];
    }
    __syncthreads();   // also covers wave-local LDS visibility

    const float4 bv = *(const float4*)&bias[q * 4];
    float4 s  = {0.f, 0.f, 0.f, 0.f};
    float4 ss = {0.f, 0.f, 0.f, 0.f};

    for (int i = 0; i < 8; ++i) {
        int v = base + i;
        if (v >= N_NODES) break;
        const int vbeg = rowptr[v];
        const int deg = rowptr[v + 1] - vbeg;
        const int off = vbeg - beg8;

        float4 acc;
        if (e == 0) {  // self loop on slot 0
            acc = *(const float4*)&hs[(size_t)v * 64 + q * 4];
        } else {
            acc.x = acc.y = acc.z = acc.w = 0.f;
        }

        int j = 0;
        if (lds_ok) {
            for (; j + 16 <= deg; j += 16) {   // 4 rows/lane in flight (4 KB/wave)
                int u0 = scol[w][off + j + e];
                int u1 = scol[w][off + j + 4 + e];
                int u2 = scol[w][off + j + 8 + e];
                int u3 = scol[w][off + j + 12 + e];
                float4 x0 = *(const float4*)&hs[(size_t)u0 * 64 + q * 4];
                float4 x1 = *(const float4*)&hs[(size_t)u1 * 64 + q * 4];
                float4 x2 = *(const float4*)&hs[(size_t)u2 * 64 + q * 4];
                float4 x3 = *(const float4*)&hs[(size_t)u3 * 64 + q * 4];
                acc.x += x0.x + x1.x + x2.x + x3.x;
                acc.y += x0.y + x1.y + x2.y + x3.y;
                acc.z += x0.z + x1.z + x2.z + x3.z;
                acc.w += x0.w + x1.w + x2.w + x3.w;
            }
            for (; j < deg; j += 4) {          // tail, predicated, clamped
                int idx = j + e;
                int ic = (idx < deg) ? idx : (deg - 1);
                int u = scol[w][off + ic];
                float4 x = *(const float4*)&hs[(size_t)u * 64 + q * 4];
                if (idx < deg) {
                    acc.x += x.x; acc.y += x.y; acc.z += x.z; acc.w += x.w;
                }
            }
        } else {       // fallback (statistically unreachable): global col
            for (; j < deg; j += 4) {
                int idx = j + e;
                int ic = (idx < deg) ? idx : (deg - 1);
                int u = col[vbeg + ic];
                float4 x = *(const float4*)&hs[(size_t)u * 64 + q * 4];
                if (idx < deg) {
                    acc.x += x.x; acc.y += x.y; acc.z += x.z; acc.w += x.w;
                }
            }
        }

        // combine the 4 edge slots (xor across lanes 16 and 32 apart)
        acc.x += __shfl_xor(acc.x, 16); acc.y += __shfl_xor(acc.y, 16);
        acc.z += __shfl_xor(acc.z, 16); acc.w += __shfl_xor(acc.w, 16);
        acc.x += __shfl_xor(acc.x, 32); acc.y += __shfl_xor(acc.y, 32);
        acc.z += __shfl_xor(acc.z, 32); acc.w += __shfl_xor(acc.w, 32);

        if (e == 0) {
            float d = dinv[v];
            float4 yv;
            yv.x = d * acc.x + bv.x;
            yv.y = d * acc.y + bv.y;
            yv.z = d * acc.z + bv.z;
            yv.w = d * acc.w + bv.w;
            *(float4*)&y[(size_t)v * 64 + q * 4] = yv;
            s.x += yv.x; s.y += yv.y; s.z += yv.z; s.w += yv.w;
            ss.x += yv.x * yv.x; ss.y += yv.y * yv.y;
            ss.z += yv.z * yv.z; ss.w += yv.w * yv.w;
        }
    }

    if (e == 0) {
        rs[w][q * 4 + 0] = s.x;  rs[w][q * 4 + 1] = s.y;
        rs[w][q * 4 + 2] = s.z;  rs[w][q * 4 + 3] = s.w;
        rss[w][q * 4 + 0] = ss.x; rss[w][q * 4 + 1] = ss.y;
        rss[w][q * 4 + 2] = ss.z; rss[w][q * 4 + 3] = ss.w;
    }
    __syncthreads();
    if (t < 64) {
        atomicAdd(&colsum[t], rs[0][t] + rs[1][t] + rs[2][t] + rs[3][t]);
        atomicAdd(&colsumsq[t], rss[0][t] + rss[1][t] + rss[2][t] + rss[3][t]);
    }
}

// ---------------- BN stats -> scale/shift ----------------
__global__ void k_stats(const float* __restrict__ colsum, const float* __restrict__ colsumsq,
                        const float* __restrict__ gamma, const float* __restrict__ beta,
                        float* __restrict__ scale, float* __restrict__ shift) {
    int f = threadIdx.x;  // 64 threads
    float mean = colsum[f] * (1.0f / N_NODES);
    float var = colsumsq[f] * (1.0f / N_NODES) - mean * mean;  // biased, torch BN
    float sc = gamma[f] * rsqrtf(var + BN_EPS);
    scale[f] = sc;
    shift[f] = beta[f] - mean * sc;
}

// ---------------- final linear 64 -> 10 (with BN+GELU of layer 3) ----------------
__global__ __launch_bounds__(256) void k_out(const float* __restrict__ h,
                                             const float* __restrict__ Wf,
                                             const float* __restrict__ bf,
                                             const float* __restrict__ scale,
                                             const float* __restrict__ shift,
                                             float* __restrict__ out, int n) {
    __shared__ float sh[64 * 65];      // padded
    __shared__ float sW[N_CLS * 65];
    __shared__ float sb[N_CLS];
    const int t = threadIdx.x;
    const int base = blockIdx.x * 64;
    for (int i = t; i < 64 * 64; i += 256) {
        int v = i >> 6, k = i & 63;
        float val = 0.f;
        if (base + v < n) {
            float raw = h[base * 64 + i];
            val = gelu_exact(raw * scale[k] + shift[k]);
        }
        sh[v * 65 + k] = val;
    }
    for (int i = t; i < N_CLS * 64; i += 256) {
        int c = i / 64, k = i % 64;
        sW[c * 65 + k] = Wf[i];
    }
    if (t < N_CLS) sb[t] = bf[t];
    __syncthreads();
    for (int o = t; o < 64 * N_CLS; o += 256) {
        int v = o / N_CLS, c = o % N_CLS;
        if (base + v < n) {
            float a = sb[c];
#pragma unroll
            for (int k = 0; k < 64; ++k) a += sh[v * 65 + k] * sW[c * 65 + k];
            out[(base + v) * N_CLS + c] = a;
        }
    }
}

extern "C" void kernel_launch(void* const* d_in, const int* in_sizes, int n_in,
                              void* d_out, int out_size, void* d_ws, size_t ws_size,
                              hipStream_t stream) {
    const float* x   = (const float*)d_in[0];
    const int*   ei  = (const int*)d_in[1];
    const float* W1  = (const float*)d_in[2];
    const float* b1  = (const float*)d_in[3];
    const float* g1  = (const float*)d_in[4];
    const float* be1 = (const float*)d_in[5];
    const float* W2  = (const float*)d_in[6];
    const float* b2  = (const float*)d_in[7];
    const float* g2  = (const float*)d_in[8];
    const float* be2 = (const float*)d_in[9];
    const float* W3  = (const float*)d_in[10];
    const float* b3  = (const float*)d_in[11];
    const float* g3  = (const float*)d_in[12];
    const float* be3 = (const float*)d_in[13];
    const float* Wf  = (const float*)d_in[14];
    const float* bfc = (const float*)d_in[15];

    const int* src = ei;            // edge_index[0]
    const int* dst = ei + N_EDGES;  // edge_index[1]

    float* A        = (float*)d_ws;              // [N,64] hs
    float* B        = A + (size_t)N_NODES * 64;  // [N,64] y
    float* dinv     = B + (size_t)N_NODES * 64;  // [N]
    int*   cnt      = (int*)(dinv + N_NODES);    // [N]
    int*   rowptr   = cnt + N_NODES;             // [N+1]
    int*   cursor   = rowptr + N_NODES + 1;      // [N]
    int*   col      = cursor + N_NODES;          // [E]
    int*   bsum     = col + N_EDGES;             // [512]
    int*   boff     = bsum + 512;                // [512]
    float* colsum   = (float*)(boff + 512);      // [64]
    float* colsumsq = colsum + 64;               // [64]
    float* scale    = colsumsq + 64;             // [64]
    float* shift    = scale + 64;                // [64]

    // ---- CSR build (once per call, reused by all 3 layers) ----
    hipMemsetAsync(cnt, 0, N_NODES * sizeof(int), stream);
    k_deg<<<(N_EDGES + 255) / 256, 256, 0, stream>>>(dst, cnt, N_EDGES);
    k_dinv<<<(N_NODES + 255) / 256, 256, 0, stream>>>(cnt, dinv, N_NODES);
    k_scan1<<<SCAN_B, 256, 0, stream>>>(cnt, bsum);
    k_scan2<<<1, 512, 0, stream>>>(bsum, boff, rowptr);
    k_scan3<<<SCAN_B, 256, 0, stream>>>(cnt, boff, rowptr, cursor);
    k_fill<<<(N_EDGES + 255) / 256, 256, 0, stream>>>(src, dst, cursor, col, N_EDGES);

    const float* Ws[3]  = {W1, W2, W3};
    const float* bs[3]  = {b1, b2, b3};
    const float* gs[3]  = {g1, g2, g3};
    const float* bes[3] = {be1, be2, be3};

    const float* hin = x;
    for (int l = 0; l < 3; ++l) {
        if (l == 0)
            k_gemm<D_IN, false><<<N_NODES / 16, 256, 0, stream>>>(hin, Ws[l], dinv,
                                                                  scale, shift, A);
        else
            k_gemm<D_H, true><<<N_NODES / 16, 256, 0, stream>>>(hin, Ws[l], dinv,
                                                                scale, shift, A);

        hipMemsetAsync(colsum, 0, 2 * 64 * sizeof(float), stream);
        k_gather<<<(N_NODES + 31) / 32, 256, 0, stream>>>(rowptr, col, A, dinv, bs[l],
                                                          B, colsum, colsumsq);
        k_stats<<<1, 64, 0, stream>>>(colsum, colsumsq, gs[l], bes[l], scale, shift);
        hin = B;
    }

    k_out<<<(N_NODES + 63) / 64, 256, 0, stream>>>(B, Wf, bfc, scale, shift,
                                                   (float*)d_out, N_NODES);
}

// Round 5
// 860.484 us; speedup vs baseline: 5.3408x; 1.0354x over previous
//
#include <hip/hip_runtime.h>
#include <hip/hip_fp16.h>
#include <math.h>

#define N_NODES 100000
#define N_EDGES 1600000
#define D_IN    128
#define D_H     64
#define N_CLS   10
#define BN_EPS  1e-5f

#define SCAN_B  391   // ceil(N_NODES / 256)
#define STAGE   512   // LDS-staged col entries per wave (8 nodes, avg 128)

__device__ __forceinline__ float gelu_exact(float x) {
    return 0.5f * x * (1.0f + erff(x * 0.70710678118654752f));
}

// accumulate 8 halves (packed in uint4) into 8 fp32 accumulators
__device__ __forceinline__ void acc8(float* a, uint4 p) {
    float2 f0 = __half22float2(*(const __half2*)&p.x);
    float2 f1 = __half22float2(*(const __half2*)&p.y);
    float2 f2 = __half22float2(*(const __half2*)&p.z);
    float2 f3 = __half22float2(*(const __half2*)&p.w);
    a[0] += f0.x; a[1] += f0.y; a[2] += f1.x; a[3] += f1.y;
    a[4] += f2.x; a[5] += f2.y; a[6] += f3.x; a[7] += f3.y;
}

// ---------------- degree / dinv ----------------
__global__ void k_deg(const int* __restrict__ dst, int* __restrict__ cnt, int E) {
    int i = blockIdx.x * blockDim.x + threadIdx.x;
    if (i < E) atomicAdd(&cnt[dst[i]], 1);
}

__global__ void k_dinv(const int* __restrict__ cnt, float* __restrict__ dinv, int n) {
    int i = blockIdx.x * blockDim.x + threadIdx.x;
    if (i < n) dinv[i] = rsqrtf((float)(cnt[i] + 1));  // +1 self loop
}

// ---------------- CSR build: 2-level exclusive scan ----------------
__global__ __launch_bounds__(256) void k_scan1(const int* __restrict__ cnt,
                                               int* __restrict__ bsum) {
    __shared__ int s[256];
    int t = threadIdx.x;
    int i = blockIdx.x * 256 + t;
    int c = (i < N_NODES) ? cnt[i] : 0;
    s[t] = c;
    __syncthreads();
    for (int off = 128; off > 0; off >>= 1) {
        if (t < off) s[t] += s[t + off];
        __syncthreads();
    }
    if (t == 0) bsum[blockIdx.x] = s[0];
}

__global__ __launch_bounds__(512) void k_scan2(const int* __restrict__ bsum,
                                               int* __restrict__ boff,
                                               int* __restrict__ rowptr) {
    __shared__ int s[512];
    int t = threadIdx.x;
    int c = (t < SCAN_B) ? bsum[t] : 0;
    s[t] = c;
    __syncthreads();
    for (int off = 1; off < 512; off <<= 1) {
        int v = (t >= off) ? s[t - off] : 0;
        __syncthreads();
        s[t] += v;
        __syncthreads();
    }
    if (t < SCAN_B) boff[t] = s[t] - c;  // exclusive
    if (t == 0) rowptr[N_NODES] = N_EDGES;
}

__global__ __launch_bounds__(256) void k_scan3(const int* __restrict__ cnt,
                                               const int* __restrict__ boff,
                                               int* __restrict__ rowptr,
                                               int* __restrict__ cursor) {
    __shared__ int s[256];
    int t = threadIdx.x;
    int i = blockIdx.x * 256 + t;
    int c = (i < N_NODES) ? cnt[i] : 0;
    s[t] = c;
    __syncthreads();
    for (int off = 1; off < 256; off <<= 1) {
        int v = (t >= off) ? s[t - off] : 0;
        __syncthreads();
        s[t] += v;
        __syncthreads();
    }
    if (i < N_NODES) {
        int ex = boff[blockIdx.x] + s[t] - c;  // exclusive global prefix
        rowptr[i] = ex;
        cursor[i] = ex;
    }
}

__global__ void k_fill(const int* __restrict__ src, const int* __restrict__ dst,
                       int* __restrict__ cursor, int* __restrict__ col, int E) {
    int e = blockIdx.x * blockDim.x + threadIdx.x;
    if (e < E) {
        int pos = atomicAdd(&cursor[dst[e]], 1);
        col[pos] = src[e];
    }
}

// ---------------- GEMM: hs = fp16( dinv[v] * (act(in[v]) @ W^T) ) ----------------
template <int DIN, bool BN>
__global__ __launch_bounds__(256) void k_gemm(const float* __restrict__ in,
                                              const float* __restrict__ W,
                                              const float* __restrict__ dinv,
                                              const float* __restrict__ scale,
                                              const float* __restrict__ shift,
                                              __half* __restrict__ out) {
    __shared__ float sW[DIN * 65];     // transposed + padded: sW[k*65 + f]
    __shared__ float sx[16][DIN];
    const int t = threadIdx.x;
    const int base = blockIdx.x * 16;  // N_NODES = 16 * 6250 exactly

    // stage W (float4 global loads, scalar LDS scatter for transpose)
    const float4* W4 = (const float4*)W;
    for (int i = t; i < 64 * DIN / 4; i += 256) {
        float4 wv = W4[i];
        int f = (i * 4) / DIN, k = (i * 4) % DIN;
        sW[(k + 0) * 65 + f] = wv.x;
        sW[(k + 1) * 65 + f] = wv.y;
        sW[(k + 2) * 65 + f] = wv.z;
        sW[(k + 3) * 65 + f] = wv.w;
    }
    // stage x (float4)
    const float4* in4 = (const float4*)(in + (size_t)base * DIN);
    float4* sx4 = (float4*)&sx[0][0];
    for (int i = t; i < 16 * DIN / 4; i += 256) {
        float4 v = in4[i];
        if (BN) {
            int k = (i * 4) & (DIN - 1);
            v.x = gelu_exact(v.x * scale[k + 0] + shift[k + 0]);
            v.y = gelu_exact(v.y * scale[k + 1] + shift[k + 1]);
            v.z = gelu_exact(v.z * scale[k + 2] + shift[k + 2]);
            v.w = gelu_exact(v.w * scale[k + 3] + shift[k + 3]);
        }
        sx4[i] = v;
    }
    __syncthreads();

    const int f = t & 63;
    const int g = t >> 6;  // wave id 0..3, each wave does 4 nodes
    float a0 = 0.f, a1 = 0.f, a2 = 0.f, a3 = 0.f;
#pragma unroll 8
    for (int k = 0; k < DIN; ++k) {
        float wv = sW[k * 65 + f];
        a0 += wv * sx[g * 4 + 0][k];
        a1 += wv * sx[g * 4 + 1][k];
        a2 += wv * sx[g * 4 + 2][k];
        a3 += wv * sx[g * 4 + 3][k];
    }
    int n0 = base + g * 4;
    out[(size_t)(n0 + 0) * 64 + f] = __float2half(dinv[n0 + 0] * a0);
    out[(size_t)(n0 + 1) * 64 + f] = __float2half(dinv[n0 + 1] * a1);
    out[(size_t)(n0 + 2) * 64 + f] = __float2half(dinv[n0 + 2] * a2);
    out[(size_t)(n0 + 3) * 64 + f] = __float2half(dinv[n0 + 3] * a3);
}

// ---------------- CSR gather (fp16 rows) + finalize + BN partial sums ----------------
// Wave layout: lane = e*8 + q; e = edge slot (0..7), q = feature octet (0..7).
// One uint4 load per lane = 8 halves; per instruction the wave fetches 8 full
// 128 B rows. Col indices staged in LDS (contiguous CSR range of the wave's
// 8 nodes). Slot partials combined via __shfl_xor(8/16/32).
__global__ __launch_bounds__(256) void k_gather(const int* __restrict__ rowptr,
                                                const int* __restrict__ col,
                                                const __half* __restrict__ hs,
                                                const float* __restrict__ dinv,
                                                const float* __restrict__ bias,
                                                float* __restrict__ y,
                                                float* __restrict__ colsum,
                                                float* __restrict__ colsumsq) {
    __shared__ int scol[4][STAGE];
    __shared__ float rs[4][64];
    __shared__ float rss[4][64];

    const int t = threadIdx.x;
    const int lane = t & 63;
    const int w = t >> 6;
    const int q = lane & 7;    // feature octet
    const int e = lane >> 3;   // edge slot
    const int base = blockIdx.x * 32 + w * 8;

    const int beg8 = rowptr[base];
    const int lim = (base + 8 <= N_NODES) ? base + 8 : N_NODES;
    const int cnt8 = rowptr[lim] - beg8;
    const bool lds_ok = (cnt8 <= STAGE);
    if (lds_ok) {
        for (int k = lane; k < cnt8; k += 64) scol[w][k] = col[beg8 + k];
    }
    __syncthreads();

    float bva[8];
#pragma unroll
    for (int r = 0; r < 8; ++r) bva[r] = bias[q * 8 + r];

    float s[8], ss[8];
#pragma unroll
    for (int r = 0; r < 8; ++r) { s[r] = 0.f; ss[r] = 0.f; }

    for (int i = 0; i < 8; ++i) {
        int v = base + i;
        if (v >= N_NODES) break;
        const int vbeg = rowptr[v];
        const int deg = rowptr[v + 1] - vbeg;
        const int off = vbeg - beg8;

        float acc[8];
#pragma unroll
        for (int r = 0; r < 8; ++r) acc[r] = 0.f;
        if (e == 0) {  // self loop on slot 0
            uint4 p = *(const uint4*)&hs[(size_t)v * 64 + q * 8];
            acc8(acc, p);
        }

        int j = 0;
        if (lds_ok) {
            for (; j + 16 <= deg; j += 16) {   // 16 edges/iter, 2 rows/lane in flight
                int u0 = scol[w][off + j + e];
                int u1 = scol[w][off + j + 8 + e];
                uint4 p0 = *(const uint4*)&hs[(size_t)u0 * 64 + q * 8];
                uint4 p1 = *(const uint4*)&hs[(size_t)u1 * 64 + q * 8];
                acc8(acc, p0);
                acc8(acc, p1);
            }
            for (; j < deg; j += 8) {          // tail, predicated, clamped
                int idx = j + e;
                int ic = (idx < deg) ? idx : (deg - 1);
                int u = scol[w][off + ic];
                uint4 p = *(const uint4*)&hs[(size_t)u * 64 + q * 8];
                if (idx < deg) acc8(acc, p);
            }
        } else {       // fallback (statistically unreachable): global col
            for (; j < deg; j += 8) {
                int idx = j + e;
                int ic = (idx < deg) ? idx : (deg - 1);
                int u = col[vbeg + ic];
                uint4 p = *(const uint4*)&hs[(size_t)u * 64 + q * 8];
                if (idx < deg) acc8(acc, p);
            }
        }

        // combine the 8 edge slots (xor across lane bits 3,4,5)
#pragma unroll
        for (int m = 8; m <= 32; m <<= 1) {
#pragma unroll
            for (int r = 0; r < 8; ++r) acc[r] += __shfl_xor(acc[r], m);
        }

        if (e == 0) {
            float d = dinv[v];
            float yv[8];
#pragma unroll
            for (int r = 0; r < 8; ++r) {
                yv[r] = d * acc[r] + bva[r];
                s[r] += yv[r];
                ss[r] += yv[r] * yv[r];
            }
            float4 y0 = {yv[0], yv[1], yv[2], yv[3]};
            float4 y1 = {yv[4], yv[5], yv[6], yv[7]};
            *(float4*)&y[(size_t)v * 64 + q * 8] = y0;
            *(float4*)&y[(size_t)v * 64 + q * 8 + 4] = y1;
        }
    }

    if (e == 0) {
#pragma unroll
        for (int r = 0; r < 8; ++r) {
            rs[w][q * 8 + r] = s[r];
            rss[w][q * 8 + r] = ss[r];
        }
    }
    __syncthreads();
    if (t < 64) {
        atomicAdd(&colsum[t], rs[0][t] + rs[1][t] + rs[2][t] + rs[3][t]);
        atomicAdd(&colsumsq[t], rss[0][t] + rss[1][t] + rss[2][t] + rss[3][t]);
    }
}

// ---------------- BN stats -> scale/shift ----------------
__global__ void k_stats(const float* __restrict__ colsum, const float* __restrict__ colsumsq,
                        const float* __restrict__ gamma, const float* __restrict__ beta,
                        float* __restrict__ scale, float* __restrict__ shift) {
    int f = threadIdx.x;  // 64 threads
    float mean = colsum[f] * (1.0f / N_NODES);
    float var = colsumsq[f] * (1.0f / N_NODES) - mean * mean;  // biased, torch BN
    float sc = gamma[f] * rsqrtf(var + BN_EPS);
    scale[f] = sc;
    shift[f] = beta[f] - mean * sc;
}

// ---------------- final linear 64 -> 10 (with BN+GELU of layer 3) ----------------
__global__ __launch_bounds__(256) void k_out(const float* __restrict__ h,
                                             const float* __restrict__ Wf,
                                             const float* __restrict__ bf,
                                             const float* __restrict__ scale,
                                             const float* __restrict__ shift,
                                             float* __restrict__ out, int n) {
    __shared__ float sh[64 * 65];      // padded
    __shared__ float sW[N_CLS * 65];
    __shared__ float sb[N_CLS];
    const int t = threadIdx.x;
    const int base = blockIdx.x * 64;
    // float4 staging; reads may run past row n into ws scratch (safe), stores guarded
    const float4* h4 = (const float4*)(h + (size_t)base * 64);
    for (int i = t; i < 64 * 64 / 4; i += 256) {
        float4 v = h4[i];
        int k = (i * 4) & 63, vv = (i * 4) >> 6;
        sh[vv * 65 + k + 0] = gelu_exact(v.x * scale[k + 0] + shift[k + 0]);
        sh[vv * 65 + k + 1] = gelu_exact(v.y * scale[k + 1] + shift[k + 1]);
        sh[vv * 65 + k + 2] = gelu_exact(v.z * scale[k + 2] + shift[k + 2]);
        sh[vv * 65 + k + 3] = gelu_exact(v.w * scale[k + 3] + shift[k + 3]);
    }
    for (int i = t; i < N_CLS * 64; i += 256) {
        int c = i / 64, k = i % 64;
        sW[c * 65 + k] = Wf[i];
    }
    if (t < N_CLS) sb[t] = bf[t];
    __syncthreads();
    for (int o = t; o < 64 * N_CLS; o += 256) {
        int v = o / N_CLS, c = o % N_CLS;
        if (base + v < n) {
            float a = sb[c];
#pragma unroll
            for (int k = 0; k < 64; ++k) a += sh[v * 65 + k] * sW[c * 65 + k];
            out[(base + v) * N_CLS + c] = a;
        }
    }
}

extern "C" void kernel_launch(void* const* d_in, const int* in_sizes, int n_in,
                              void* d_out, int out_size, void* d_ws, size_t ws_size,
                              hipStream_t stream) {
    const float* x   = (const float*)d_in[0];
    const int*   ei  = (const int*)d_in[1];
    const float* W1  = (const float*)d_in[2];
    const float* b1  = (const float*)d_in[3];
    const float* g1  = (const float*)d_in[4];
    const float* be1 = (const float*)d_in[5];
    const float* W2  = (const float*)d_in[6];
    const float* b2  = (const float*)d_in[7];
    const float* g2  = (const float*)d_in[8];
    const float* be2 = (const float*)d_in[9];
    const float* W3  = (const float*)d_in[10];
    const float* b3  = (const float*)d_in[11];
    const float* g3  = (const float*)d_in[12];
    const float* be3 = (const float*)d_in[13];
    const float* Wf  = (const float*)d_in[14];
    const float* bfc = (const float*)d_in[15];

    const int* src = ei;            // edge_index[0]
    const int* dst = ei + N_EDGES;  // edge_index[1]

    char*   w0      = (char*)d_ws;
    __half* A       = (__half*)w0;                              // [N,64] hs (fp16)
    float*  B       = (float*)(w0 + (size_t)N_NODES * 64 * 2);  // [N,64] y (fp32)
    float*  dinv    = B + (size_t)N_NODES * 64;                 // [N]
    int*    cnt     = (int*)(dinv + N_NODES);                   // [N]
    int*    rowptr  = cnt + N_NODES;                            // [N+1]
    int*    cursor  = rowptr + N_NODES + 1;                     // [N]
    int*    col     = cursor + N_NODES;                         // [E]
    int*    bsum    = col + N_EDGES;                            // [512]
    int*    boff    = bsum + 512;                               // [512]
    float*  colsum  = (float*)(boff + 512);                     // [64]
    float*  colsumsq= colsum + 64;                              // [64]
    float*  scale   = colsumsq + 64;                            // [64]
    float*  shift   = scale + 64;                               // [64]

    // ---- CSR build (once per call, reused by all 3 layers) ----
    hipMemsetAsync(cnt, 0, N_NODES * sizeof(int), stream);
    k_deg<<<(N_EDGES + 255) / 256, 256, 0, stream>>>(dst, cnt, N_EDGES);
    k_dinv<<<(N_NODES + 255) / 256, 256, 0, stream>>>(cnt, dinv, N_NODES);
    k_scan1<<<SCAN_B, 256, 0, stream>>>(cnt, bsum);
    k_scan2<<<1, 512, 0, stream>>>(bsum, boff, rowptr);
    k_scan3<<<SCAN_B, 256, 0, stream>>>(cnt, boff, rowptr, cursor);
    k_fill<<<(N_EDGES + 255) / 256, 256, 0, stream>>>(src, dst, cursor, col, N_EDGES);

    const float* Ws[3]  = {W1, W2, W3};
    const float* bs[3]  = {b1, b2, b3};
    const float* gs[3]  = {g1, g2, g3};
    const float* bes[3] = {be1, be2, be3};

    const float* hin = x;
    for (int l = 0; l < 3; ++l) {
        if (l == 0)
            k_gemm<D_IN, false><<<N_NODES / 16, 256, 0, stream>>>(hin, Ws[l], dinv,
                                                                  scale, shift, A);
        else
            k_gemm<D_H, true><<<N_NODES / 16, 256, 0, stream>>>(hin, Ws[l], dinv,
                                                                scale, shift, A);

        hipMemsetAsync(colsum, 0, 2 * 64 * sizeof(float), stream);
        k_gather<<<(N_NODES + 31) / 32, 256, 0, stream>>>(rowptr, col, A, dinv, bs[l],
                                                          B, colsum, colsumsq);
        k_stats<<<1, 64, 0, stream>>>(colsum, colsumsq, gs[l], bes[l], scale, shift);
        hin = B;
    }

    k_out<<<(N_NODES + 63) / 64, 256, 0, stream>>>(B, Wf, bfc, scale, shift,
                                                   (float*)d_out, N_NODES);
}